// Round 5
// baseline (203.437 us; speedup 1.0000x reference)
//
#include <hip/hip_runtime.h>
#include <hip/hip_bf16.h>

// AttentionRefinementModule: cumsum(excl,t) -> conv5x5(16->32) -> +b,relu ->
// mask0 -> 1x1 proj(32->8) -> masked BN -> permute.
// cumsum inputs first (conv commutes with cumsum); MFMA conv over 1024 images.
// R5: explicit depth-2 software pipeline (B global + A LDS prefetch into
// rotating regs) — R4 showed pipes serialized (sum of utils ~100%) because
// loads were consumed right after issue (VGPR=84, no prefetch headroom).

typedef __attribute__((ext_vector_type(4))) float f32x4;
typedef __attribute__((ext_vector_type(2))) float f32x2;
typedef __attribute__((ext_vector_type(8))) short short8;
typedef __attribute__((ext_vector_type(8))) unsigned short u16x8;

#define B_   8
#define NH   8
#define T_   128
#define H_   32
#define W_   64
#define L_   2048
#define CIN  16
#define DCC  32
#define WSTR 420   // K stride (elems) of weight rows

__device__ __forceinline__ unsigned short f2h(float f){
  _Float16 h = (_Float16)f;
  return __builtin_bit_cast(unsigned short, h);
}
__device__ __forceinline__ float h2f(unsigned short u){
  _Float16 h = __builtin_bit_cast(_Float16, u);
  return (float)h;
}
// 2-bit swizzle: bits[4:5] ^= bits[7:8]. Adding multiples of 512 commutes,
// so ds_read immediate offsets (mt steps of 512 B) remain valid.
__device__ __forceinline__ int swz(int a){ return a ^ ((a >> 3) & 0x30); }

// ---------------- K0: exclusive cumsum over t, fp32 -> fp16 (2 px/thread) ---
// 512 blocks = 2 blocks/CU = 8 waves/CU; unroll 8 for memory-level parallelism.
__global__ void k_cumsum(const float* __restrict__ prev,
                         const float* __restrict__ curr,
                         unsigned* __restrict__ cum1)
{
  int gid = blockIdx.x * 256 + threadIdx.x;      // 0..131071
  int p2 = gid & 1023;                           // pair: px = 2*p2
  int ci = (gid >> 10) & 15;
  int b  = gid >> 14;
  const float* src = ((ci < 8)
      ? prev + ((size_t)(b*8 + ci) * T_) * L_
      : curr + ((size_t)(b*8 + ci - 8) * T_) * L_) + p2*2;
  unsigned* dst = cum1 + ((size_t)(b*CIN + ci) * T_) * (L_/2) + p2;
  float a0 = 0.f, a1 = 0.f;
  #pragma unroll 8
  for (int t = 0; t < T_; t++){
    dst[(size_t)t * (L_/2)] = (unsigned)f2h(a0) | ((unsigned)f2h(a1) << 16);
    f32x2 v = *(const f32x2*)(src + (size_t)t * L_);
    a0 += v.x; a1 += v.y;
  }
}

// ---------------- K_prep: weights->fp16 layout + mask convert (merged) -----
// blocks 0..31: Wt row co; block 32: Pt; blocks 33..48: mask chunk
__global__ void k_prep(const float* __restrict__ convw,
                       const float* __restrict__ projw,
                       const void* __restrict__ mraw,
                       unsigned short* __restrict__ Wt,
                       unsigned short* __restrict__ Pt,
                       unsigned char* __restrict__ mB,
                       float* __restrict__ cntOut)
{
  int tid = threadIdx.x;
  int blk = blockIdx.x;
  if (blk < 32){
    int co = blk;
    for (int k = tid; k < WSTR; k += 256){
      float v = 0.f;
      if (k < 400){
        int tap = k >> 4, ci = k & 15;
        int dy = tap / 5, dx = tap - dy*5;
        v = convw[(((co*CIN + ci)*5 + dy)*5) + dx];
      }
      Wt[co*WSTR + k] = f2h(v);
    }
  } else if (blk == 32){
    // Pt[n][q] 16x32, rows 8..15 zero, col-permuted: q -> co = 16*(q&1)+(q>>1)
    for (int idx = tid; idx < 16*32; idx += 256){
      int n = idx >> 5, q = idx & 31;
      float v = (n < 8) ? projw[n*32 + 16*(q & 1) + (q >> 1)] : 0.f;
      Pt[idx] = f2h(v);
    }
  } else {
    __shared__ int s_flags;
    __shared__ int s_cnt;
    if (tid == 0){ s_flags = 0; s_cnt = 0; }
    __syncthreads();
    const unsigned* w = (const unsigned*)mraw;
    int fl = 0;
    for (int i = tid; i < 4096; i += 256){       // scan 16KB worth of words
      unsigned v = w[i];
      if (v == 0x3F800000u) fl |= 2;             // float 1.0 pattern
      else if (v > 1u)      fl |= 1;             // packed-byte pattern
      else if (v == 1u)     fl |= 4;             // i32 "true" pattern
    }
    if (fl) atomicOr(&s_flags, fl);
    __syncthreads();
    int flags = s_flags;
    int mode = (flags & 1) ? 0 : ((flags & 2) ? 2 : ((flags & 4) ? 1 : 0));
    int c = 0;
    int base = (blk - 33) * 1024;
    for (int k = 0; k < 4; k++){
      int i = base + k*256 + tid;
      int m;
      if (mode == 0)      m = (((const unsigned char*)mraw)[i] != 0);
      else if (mode == 2) m = (((const float*)mraw)[i] != 0.f);
      else                m = (((const int*)mraw)[i] != 0);
      mB[i] = (unsigned char)m;
      c += 1 - m;
    }
    atomicAdd(&s_cnt, c);
    __syncthreads();
    if (tid == 0) atomicAdd(cntOut, 128.0f * (float)s_cnt);
  }
}

// ---------------- K_conv: MFMA conv + bias/relu/mask + proj + stats --------
// One block = half of one (b,t) image (16 rows). 4 waves x 256px each.
// Weights read from global (L1-resident, 26.9KB); img staged in LDS.
__global__ __launch_bounds__(256, 3) void k_conv(
    const unsigned short* __restrict__ cumIn,
    const unsigned short* __restrict__ Wt,
    const unsigned short* __restrict__ Pt,
    const unsigned char* __restrict__ mB,
    const float* __restrict__ convb,
    unsigned short* __restrict__ cov,
    float* __restrict__ slots)
{
  __shared__ alignas(16) unsigned short img[20*68*16];   // swizzled, 43520 B
  __shared__ alignas(16) unsigned short plds[16*32];     // 1024 B
  __shared__ alignas(16) unsigned sval[4][16*20];        // per-wave packed, 5120 B
  __shared__ unsigned long long mbl[16];                 // bit mask, 1024 px

  const int tid  = threadIdx.x;
  const int bid  = blockIdx.x;
  const int half = bid & 1;
  const int bt   = bid >> 1;
  const int t    = bt & 127;
  const int b    = bt >> 7;
  const int ylo  = half * 16;
  const int lane = tid & 63;
  const int wv   = tid >> 6;
  const int mrow = lane & 15;
  const int kb   = lane >> 4;

  // mask bits for this half-image: wave 0 ballots 16 x 64 px
  if (wv == 0){
    #pragma unroll
    for (int k2 = 0; k2 < 16; k2++){
      int m = mB[b*L_ + half*1024 + k2*64 + lane];
      unsigned long long bal = __ballot(m != 0);
      if (lane == 0) mbl[k2] = bal;
    }
  } else if (wv == 1){
    const uint4* srcp = (const uint4*)Pt;
    uint4* dstp = (uint4*)plds;
    for (int i = lane; i < 64; i += 64) dstp[i] = srcp[i];
  }

  // zero-fill x-halo columns (x in {-2,-1,64,65} is always OOB -> 0)
  for (int it = tid; it < 640; it += 256){
    int cp  = it & 7;
    int xxi = (it >> 3) & 3;
    int yy  = it >> 5;                       // 0..19
    int xx  = (xxi < 2) ? xxi : 64 + xxi;    // 0,1,66,67
    int ad  = ((yy*68 + xx)*16 + 2*cp)*2;
    *(unsigned*)((char*)img + swz(ad)) = 0u;
  }
  // stage interior: issue ALL 10 global loads first (one latency, not five),
  // then pack+write to LDS. thread = (yy, ci-pair, x-chunk of 8).
  {
    u16x8 sv0[5], sv1[5];
    int sb_[5];
    #pragma unroll
    for (int iter = 0; iter < 5; iter++){
      int it = iter*256 + tid;               // 0..1279
      int xc = it & 7;
      int cp = (it >> 3) & 7;
      int yy = it >> 6;                      // 0..19
      int y  = ylo - 2 + yy;
      sv0[iter] = (u16x8)0; sv1[iter] = (u16x8)0;
      if (y >= 0 && y < H_){
        const unsigned short* r0 = cumIn + (((size_t)(b*CIN + 2*cp) * T_ + t) * L_) + y*W_ + xc*8;
        sv0[iter] = *(const u16x8*)r0;
        sv1[iter] = *(const u16x8*)(r0 + (size_t)T_ * L_);   // next ci plane
      }
      sb_[iter] = ((yy*68 + 2 + xc*8)*16 + 2*cp)*2;
    }
    #pragma unroll
    for (int iter = 0; iter < 5; iter++){
      #pragma unroll
      for (int j = 0; j < 8; j++){
        unsigned wd = (unsigned)sv0[iter][j] | ((unsigned)sv1[iter][j] << 16);
        *(unsigned*)((char*)img + swz(sb_[iter] + j*32)) = wd;
      }
    }
  }
  __syncthreads();

  const float cb0 = convb[mrow];
  const float cb1 = convb[mrow + 16];
  const short8 pbf = *(const short8*)&plds[mrow*32 + kb*8];  // proj B-frag
  const unsigned short* Wg = Wt + mrow*WSTR + kb*8;          // weight row base
  const char* imgc = (const char*)img;

  // per-lane tap byte-offsets for all 13 k-steps
  int offs_[13];
  #pragma unroll
  for (int ks = 0; ks < 13; ks++){
    int tap = ks*2 + (kb >> 1);
    if (tap > 24) tap = 24;                  // k>=400: W=0, A value ignored
    int dy = tap / 5, dx = tap - dy*5;
    offs_[ks] = (dy*68 + dx)*32 + (kb & 1)*16;
  }

  float ssum = 0.f, ssq = 0.f;

  #pragma unroll 1
  for (int c = 0; c < 2; c++){
    // opaque zero: anchors prefetch loads inside this c-iteration (no LICM)
    int wofs = 0;
    asm volatile("" : "+v"(wofs));
    const int pbase = wv*256 + c*128;
    const unsigned long long mw0 = mbl[(pbase >> 6)];
    const unsigned long long mw1 = mbl[(pbase >> 6) + 1];
    const int base_u = ((pbase >> 6)*68 + mrow)*32;   // unswizzled byte base
    f32x4 acc[8][2];
    #pragma unroll
    for (int mt = 0; mt < 8; mt++){ acc[mt][0] = (f32x4)0.f; acc[mt][1] = (f32x4)0.f; }

    // ---- depth-2 software pipeline over ks: prefetch B (global) + A (LDS)
    short8 nbfa = *(const short8*)(Wg + wofs);
    short8 nbfb = *(const short8*)(Wg + wofs + 6720);
    short8 an[8];
    {
      const char* p0 = imgc + swz(base_u + offs_[0]);
      const char* p1 = imgc + swz(base_u + 2176 + offs_[0]);
      an[0] = *(const short8*)(p0);
      an[1] = *(const short8*)(p0 + 512);
      an[2] = *(const short8*)(p0 + 1024);
      an[3] = *(const short8*)(p0 + 1536);
      an[4] = *(const short8*)(p1);
      an[5] = *(const short8*)(p1 + 512);
      an[6] = *(const short8*)(p1 + 1024);
      an[7] = *(const short8*)(p1 + 1536);
    }
    #pragma unroll
    for (int ks = 0; ks < 13; ks++){
      short8 bfa = nbfa, bfb = nbfb;
      short8 a[8];
      #pragma unroll
      for (int i = 0; i < 8; i++) a[i] = an[i];
      if (ks < 12){
        nbfa = *(const short8*)(Wg + wofs + (ks+1)*32);          // co 0..15
        nbfb = *(const short8*)(Wg + wofs + 6720 + (ks+1)*32);   // co 16..31
        const char* p0 = imgc + swz(base_u + offs_[ks+1]);
        const char* p1 = imgc + swz(base_u + 2176 + offs_[ks+1]);
        an[0] = *(const short8*)(p0);
        an[1] = *(const short8*)(p0 + 512);
        an[2] = *(const short8*)(p0 + 1024);
        an[3] = *(const short8*)(p0 + 1536);
        an[4] = *(const short8*)(p1);
        an[5] = *(const short8*)(p1 + 512);
        an[6] = *(const short8*)(p1 + 1024);
        an[7] = *(const short8*)(p1 + 1536);
      }
      __builtin_amdgcn_s_setprio(1);
      #pragma unroll
      for (int mt = 0; mt < 8; mt++){
        acc[mt][0] = __builtin_amdgcn_mfma_f32_16x16x32_f16(a[mt], bfa, acc[mt][0], 0, 0, 0);
        acc[mt][1] = __builtin_amdgcn_mfma_f32_16x16x32_f16(a[mt], bfb, acc[mt][1], 0, 0, 0);
      }
      __builtin_amdgcn_s_setprio(0);
    }

    // epilogue: bias+relu+mask -> packed fp16 pairs in sval (transpose) ->
    // proj MFMA (K=32, P columns pre-permuted) -> cov store + stats.
    // Single buffer: proj(mt-1) reads are issued BEFORE store(mt) writes;
    // same-wave LDS ops complete in order, compiler preserves aliased order.
    unsigned* sv = &sval[wv][0];
    #pragma unroll
    for (int mt = 0; mt <= 8; mt++){
      if (mt >= 1){
        const int m = mt - 1;
        short8 pa = *(const short8*)&sv[mrow*20 + kb*4];
        f32x4 pc = (f32x4)0.f;
        pc = __builtin_amdgcn_mfma_f32_16x16x32_f16(pa, pbf, pc, 0, 0, 0);
        if (mrow < 8){
          const unsigned long long mwm = (m < 4) ? mw0 : mw1;
          size_t covbase = (((size_t)bt*NH + mrow) * L_) + half*1024 + pbase + m*16 + kb*4;
          uint2 st;
          st.x = (unsigned)f2h(pc[0]) | ((unsigned)f2h(pc[1]) << 16);
          st.y = (unsigned)f2h(pc[2]) | ((unsigned)f2h(pc[3]) << 16);
          *(uint2*)&cov[covbase] = st;
          #pragma unroll
          for (int r = 0; r < 4; r++){
            int bi = (m*16 + kb*4 + r) & 63;
            if (!((mwm >> bi) & 1)){ ssum += pc[r]; ssq += pc[r]*pc[r]; }
          }
        }
      }
      if (mt < 8){
        const unsigned long long mw = (mt < 4) ? mw0 : mw1;
        #pragma unroll
        for (int r = 0; r < 4; r++){
          int bi  = (mt*16 + kb*4 + r) & 63;
          int msk = (int)((mw >> bi) & 1);
          float v0 = fmaxf(acc[mt][0][r] + cb0, 0.f);
          float v1 = fmaxf(acc[mt][1][r] + cb1, 0.f);
          if (msk){ v0 = 0.f; v1 = 0.f; }
          unsigned pd = (unsigned)f2h(v0) | ((unsigned)f2h(v1) << 16);
          sv[(kb*4 + r)*20 + mrow] = pd;
        }
      }
    }
  }

  // stats: fold kb groups (lanes mrow, mrow+16, mrow+32, mrow+48)
  ssum += __shfl_xor(ssum, 16);
  ssum += __shfl_xor(ssum, 32);
  ssq  += __shfl_xor(ssq, 16);
  ssq  += __shfl_xor(ssq, 32);
  if (lane < 8){
    atomicAdd(&slots[(bid & 7)*16 + lane],     ssum);
    atomicAdd(&slots[(bid & 7)*16 + 8 + lane], ssq);
  }
}

// ---------------- K_stats: finalize BN -> per-channel affine ---------------
__global__ void k_stats(const float* __restrict__ slots,
                        const float* __restrict__ cntp,
                        const float* __restrict__ gamma,
                        const float* __restrict__ beta,
                        float* __restrict__ ab)
{
  int tid = threadIdx.x;
  if (tid < 8){
    double s = 0.0, q = 0.0;
    for (int i = 0; i < 8; i++){
      s += (double)slots[i*16 + tid];
      q += (double)slots[i*16 + 8 + tid];
    }
    double cnt  = (double)fmaxf(*cntp, 1.0f);
    double mean = s / cnt;
    double var  = q / cnt - mean*mean;
    float inv = (float)(1.0 / sqrt(var + 1e-5));
    float A = gamma[tid] * inv;
    float Bc = beta[tid] - (float)mean * A;
    ab[tid]     = A;
    ab[8 + tid] = Bc;
  }
}

// ---------------- K_out: normalize + (b,t,n)->(b,n,t) permute --------------
__global__ void k_out(const unsigned short* __restrict__ cov,
                      const unsigned char* __restrict__ mB,
                      const float* __restrict__ ab,
                      float* __restrict__ out)
{
  size_t gid = (size_t)blockIdx.x * 256 + threadIdx.x;
  size_t e = gid * 8;                               // out element base
  int px = (int)(e & 2047);
  size_t r = e >> 11;
  int t = (int)(r & 127); r >>= 7;
  int n = (int)(r & 7);
  int b = (int)(r >> 3);
  const unsigned short* cp = cov + ((((size_t)b*T_ + t)*NH + n) << 11) + px;
  u16x8 cv = *(const u16x8*)cp;
  unsigned long long mm = *(const unsigned long long*)(mB + (size_t)b*L_ + px);
  float A = ab[n], Bc = ab[8 + n];
  float res[8];
  #pragma unroll
  for (int j = 0; j < 8; j++){
    float v = h2f(cv[j]);
    res[j] = ((mm >> (8*j)) & 0xFFull) ? v : (A*v + Bc);  // masked: raw (==0)
  }
  f32x4* o = (f32x4*)(out + e);
  o[0] = (f32x4){res[0], res[1], res[2], res[3]};
  o[1] = (f32x4){res[4], res[5], res[6], res[7]};
}

// ---------------------------------------------------------------------------
extern "C" void kernel_launch(void* const* d_in, const int* in_sizes, int n_in,
                              void* d_out, int out_size, void* d_ws, size_t ws_size,
                              hipStream_t stream)
{
  const float* prev  = (const float*)d_in[0];
  const float* curr  = (const float*)d_in[1];
  const void*  mraw  = d_in[2];
  // d_in[3] = h (unused, constant 32)
  const float* convw = (const float*)d_in[4];
  const float* convb = (const float*)d_in[5];
  const float* projw = (const float*)d_in[6];
  const float* gamma = (const float*)d_in[7];
  const float* beta  = (const float*)d_in[8];
  float* out = (float*)d_out;

  char* ws = (char*)d_ws;
  // layout (bytes): cumIn 67108864 | cov 33554432 | mB 16384 | Wt 26880 |
  //                 Pt 1024 | slots 512 | cnt 64 | ab 64
  unsigned short* cumIn = (unsigned short*)(ws);
  unsigned short* cov   = (unsigned short*)(ws + 67108864);
  unsigned char*  mB    = (unsigned char*) (ws + 100663296);
  unsigned short* Wt    = (unsigned short*)(ws + 100679680);
  unsigned short* Pt    = (unsigned short*)(ws + 100706560);
  float* slots          = (float*)(ws + 100707584);
  float* cntp           = (float*)(ws + 100708096);
  float* ab             = (float*)(ws + 100708160);
  if (ws_size < (size_t)100708224) return;   // clean failure if ws too small

  hipMemsetAsync(slots, 0, 640, stream);     // slots + cntp
  k_prep  <<<49,   256, 0, stream>>>(convw, projw, mraw, Wt, Pt, mB, cntp);
  k_cumsum<<<512,  256, 0, stream>>>(prev, curr, (unsigned*)cumIn);
  k_conv  <<<2048, 256, 0, stream>>>(cumIn, Wt, Pt, mB, convb, cov, slots);
  k_stats <<<1,    64,  0, stream>>>(slots, cntp, gamma, beta, ab);
  k_out   <<<8192, 256, 0, stream>>>(cov, mB, ab, out);
}

// Round 6
// 171.003 us; speedup vs baseline: 1.1897x; 1.1897x over previous
//
#include <hip/hip_runtime.h>
#include <hip/hip_bf16.h>

// AttentionRefinementModule: cumsum(excl,t) -> conv5x5(16->32) -> +b,relu ->
// mask0 -> 1x1 proj(32->8) -> masked BN -> permute.
// cumsum inputs first (conv commutes with cumsum); MFMA conv over 1024 images.
// R6: revert R5 pipeline (it spilled to scratch: FETCH +80MB). Back to R4 loop.
// New: dy-paired K-grouping — each K=32 MFMA slice = {(dy,dx),(dy+1,dx)}x16ci,
// so the two 512B half-windows of each A ds_read_b128 are 2176B apart
// (fully distinct bytes) instead of 32B (50% aliased) => fewer LDS conflicts.

typedef __attribute__((ext_vector_type(4))) float f32x4;
typedef __attribute__((ext_vector_type(8))) short short8;
typedef __attribute__((ext_vector_type(8))) unsigned short u16x8;

#define B_   8
#define NH   8
#define T_   128
#define H_   32
#define W_   64
#define L_   2048
#define CIN  16
#define DCC  32
#define WSTR 420   // K stride (elems) of weight rows (416 used + pad)

__device__ __forceinline__ unsigned short f2h(float f){
  _Float16 h = (_Float16)f;
  return __builtin_bit_cast(unsigned short, h);
}
__device__ __forceinline__ float h2f(unsigned short u){
  _Float16 h = __builtin_bit_cast(_Float16, u);
  return (float)h;
}
// 2-bit swizzle: bits[4:5] ^= bits[7:8]. Adding multiples of 512 commutes,
// so ds_read immediate offsets (mt steps of 512 B) remain valid.
__device__ __forceinline__ int swz(int a){ return a ^ ((a >> 3) & 0x30); }

// ---------------- K_front: cumsum (blocks 0..255) + prep (256..304) --------
__global__ void k_front(const float* __restrict__ prev,
                        const float* __restrict__ curr,
                        uint2* __restrict__ cum2,
                        const float* __restrict__ convw,
                        const float* __restrict__ projw,
                        const void* __restrict__ mraw,
                        unsigned short* __restrict__ Wt,
                        unsigned short* __restrict__ Pt,
                        unsigned char* __restrict__ mB,
                        float* __restrict__ cntOut)
{
  int tid = threadIdx.x;
  int blk = blockIdx.x;
  if (blk < 256){
    // exclusive cumsum over t, fp32 -> fp16, 4 px/thread
    int gid = blk * 256 + tid;                   // 0..65535
    int p4 = gid & 511;                          // quad: px = 4*p4
    int ci = (gid >> 9) & 15;
    int b  = gid >> 13;
    const float* src = ((ci < 8)
        ? prev + ((size_t)(b*8 + ci) * T_) * L_
        : curr + ((size_t)(b*8 + ci - 8) * T_) * L_) + p4*4;
    uint2* dst = cum2 + ((size_t)(b*CIN + ci) * T_) * (L_/4) + p4;
    float a0 = 0.f, a1 = 0.f, a2 = 0.f, a3 = 0.f;
    #pragma unroll 4
    for (int t = 0; t < T_; t++){
      uint2 o;
      o.x = (unsigned)f2h(a0) | ((unsigned)f2h(a1) << 16);
      o.y = (unsigned)f2h(a2) | ((unsigned)f2h(a3) << 16);
      dst[(size_t)t * (L_/4)] = o;               // exclusive
      f32x4 v = *(const f32x4*)(src + (size_t)t * L_);
      a0 += v.x; a1 += v.y; a2 += v.z; a3 += v.w;
    }
    return;
  }
  int blk2 = blk - 256;
  if (blk2 < 32){
    // Wt row co, dy-paired K layout:
    // k = g*32 + kb*8 + j ; h = kb>>1 ; ci = (kb&1)*8 + j
    // g<10: dx = g>>1, dy = (g&1)*2 + h
    // g>=10: dy = 4, dx = 2*(g-10) + h  (dx>4 => zero pad)
    int co = blk2;
    for (int k = tid; k < WSTR; k += 256){
      float v = 0.f;
      if (k < 416){
        int g  = k >> 5, kk = k & 31;
        int kb = kk >> 3, j = kk & 7;
        int ci = (kb & 1)*8 + j;
        int h  = kb >> 1;
        int dy, dx, valid = 1;
        if (g < 10){ dx = g >> 1; dy = (g & 1)*2 + h; }
        else { dy = 4; dx = 2*(g - 10) + h; if (dx > 4) valid = 0; }
        if (valid) v = convw[(((co*CIN + ci)*5 + dy)*5) + dx];
      }
      Wt[co*WSTR + k] = f2h(v);
    }
  } else if (blk2 == 32){
    // Pt[n][q] 16x32, rows 8..15 zero, col-permuted: q -> co = 16*(q&1)+(q>>1)
    for (int idx = tid; idx < 16*32; idx += 256){
      int n = idx >> 5, q = idx & 31;
      float v = (n < 8) ? projw[n*32 + 16*(q & 1) + (q >> 1)] : 0.f;
      Pt[idx] = f2h(v);
    }
  } else {
    __shared__ int s_flags;
    __shared__ int s_cnt;
    if (tid == 0){ s_flags = 0; s_cnt = 0; }
    __syncthreads();
    const unsigned* w = (const unsigned*)mraw;
    int fl = 0;
    for (int i = tid; i < 4096; i += 256){       // scan 16KB worth of words
      unsigned v = w[i];
      if (v == 0x3F800000u) fl |= 2;             // float 1.0 pattern
      else if (v > 1u)      fl |= 1;             // packed-byte pattern
      else if (v == 1u)     fl |= 4;             // i32 "true" pattern
    }
    if (fl) atomicOr(&s_flags, fl);
    __syncthreads();
    int flags = s_flags;
    int mode = (flags & 1) ? 0 : ((flags & 2) ? 2 : ((flags & 4) ? 1 : 0));
    int c = 0;
    int base = (blk2 - 33) * 1024;
    for (int k = 0; k < 4; k++){
      int i = base + k*256 + tid;
      int m;
      if (mode == 0)      m = (((const unsigned char*)mraw)[i] != 0);
      else if (mode == 2) m = (((const float*)mraw)[i] != 0.f);
      else                m = (((const int*)mraw)[i] != 0);
      mB[i] = (unsigned char)m;
      c += 1 - m;
    }
    atomicAdd(&s_cnt, c);
    __syncthreads();
    if (tid == 0) atomicAdd(cntOut, 128.0f * (float)s_cnt);
  }
}

// ---------------- K_conv: MFMA conv + bias/relu/mask + proj + stats --------
// One block = half of one (b,t) image (16 rows). 4 waves x 256px each.
// Weights read from global (L1-resident, 26.9KB); img staged in LDS.
__global__ __launch_bounds__(256, 3) void k_conv(
    const unsigned short* __restrict__ cumIn,
    const unsigned short* __restrict__ Wt,
    const unsigned short* __restrict__ Pt,
    const unsigned char* __restrict__ mB,
    const float* __restrict__ convb,
    unsigned short* __restrict__ cov,
    float* __restrict__ slots)
{
  __shared__ alignas(16) unsigned short img[20*68*16];   // swizzled, 43520 B
  __shared__ alignas(16) unsigned short plds[16*32];     // 1024 B
  __shared__ alignas(16) unsigned sval[4][16*20];        // per-wave packed, 5120 B
  __shared__ unsigned long long mbl[16];                 // bit mask, 1024 px

  const int tid  = threadIdx.x;
  const int bid  = blockIdx.x;
  const int half = bid & 1;
  const int bt   = bid >> 1;
  const int t    = bt & 127;
  const int b    = bt >> 7;
  const int ylo  = half * 16;
  const int lane = tid & 63;
  const int wv   = tid >> 6;
  const int mrow = lane & 15;
  const int kb   = lane >> 4;

  // mask bits for this half-image: wave 0 ballots 16 x 64 px
  if (wv == 0){
    #pragma unroll
    for (int k2 = 0; k2 < 16; k2++){
      int m = mB[b*L_ + half*1024 + k2*64 + lane];
      unsigned long long bal = __ballot(m != 0);
      if (lane == 0) mbl[k2] = bal;
    }
  } else if (wv == 1){
    const uint4* srcp = (const uint4*)Pt;
    uint4* dstp = (uint4*)plds;
    for (int i = lane; i < 64; i += 64) dstp[i] = srcp[i];
  }

  // zero-fill x-halo columns (x in {-2,-1,64,65} is always OOB -> 0)
  for (int it = tid; it < 640; it += 256){
    int cp  = it & 7;
    int xxi = (it >> 3) & 3;
    int yy  = it >> 5;                       // 0..19
    int xx  = (xxi < 2) ? xxi : 64 + xxi;    // 0,1,66,67
    int ad  = ((yy*68 + xx)*16 + 2*cp)*2;
    *(unsigned*)((char*)img + swz(ad)) = 0u;
  }
  // stage interior: thread = (yy, ci-pair, x-chunk of 8); 16B coalesced loads,
  // b32 LDS writes (2 ci packed), 2-bit swizzle
  #pragma unroll
  for (int iter = 0; iter < 5; iter++){
    int it = iter*256 + tid;                 // 0..1279
    int xc = it & 7;
    int cp = (it >> 3) & 7;
    int yy = it >> 6;                        // 0..19
    int y  = ylo - 2 + yy;
    u16x8 v0 = (u16x8)0, v1 = (u16x8)0;
    if (y >= 0 && y < H_){
      const unsigned short* r0 = cumIn + (((size_t)(b*CIN + 2*cp) * T_ + t) * L_) + y*W_ + xc*8;
      v0 = *(const u16x8*)r0;
      v1 = *(const u16x8*)(r0 + (size_t)T_ * L_);   // next ci plane
    }
    int sbase = ((yy*68 + 2 + xc*8)*16 + 2*cp)*2;
    #pragma unroll
    for (int j = 0; j < 8; j++){
      unsigned wd = (unsigned)v0[j] | ((unsigned)v1[j] << 16);
      int ad = sbase + j*32;
      *(unsigned*)((char*)img + swz(ad)) = wd;
    }
  }
  __syncthreads();

  const float cb0 = convb[mrow];
  const float cb1 = convb[mrow + 16];
  const short8 pbf = *(const short8*)&plds[mrow*32 + kb*8];  // proj B-frag
  const unsigned short* Wg = Wt + mrow*WSTR + kb*8;          // weight row base
  const char* imgc = (const char*)img;

  // per-lane tap byte-offsets for all 13 k-groups (dy-paired layout)
  int offs_[13];
  {
    const int h = kb >> 1;
    #pragma unroll
    for (int g = 0; g < 13; g++){
      int dy, dx;
      if (g < 10){ dx = g >> 1; dy = (g & 1)*2 + h; }
      else { dy = 4; dx = 2*(g - 10) + h; if (dx > 4) dx = 4; } // pad: W=0
      offs_[g] = (dy*68 + dx)*32 + (kb & 1)*16;
    }
  }

  float ssum = 0.f, ssq = 0.f;

  #pragma unroll 1
  for (int c = 0; c < 2; c++){
    // opaque zero: keeps B-loads inside the c-loop (blocks LICM => VGPR fit)
    int wofs = 0;
    asm volatile("" : "+v"(wofs));
    const int pbase = wv*256 + c*128;
    const unsigned long long mw0 = mbl[(pbase >> 6)];
    const unsigned long long mw1 = mbl[(pbase >> 6) + 1];
    const int base_u = ((pbase >> 6)*68 + mrow)*32;   // unswizzled byte base
    f32x4 acc[8][2];
    #pragma unroll
    for (int mt = 0; mt < 8; mt++){ acc[mt][0] = (f32x4)0.f; acc[mt][1] = (f32x4)0.f; }

    #pragma unroll
    for (int ks = 0; ks < 13; ks++){
      short8 bfa = *(const short8*)(Wg + wofs + ks*32);          // co 0..15
      short8 bfb = *(const short8*)(Wg + wofs + 6720 + ks*32);   // co 16..31
      const char* p0 = imgc + swz(base_u + offs_[ks]);
      const char* p1 = imgc + swz(base_u + 2176 + offs_[ks]);
      short8 a[8];
      a[0] = *(const short8*)(p0);
      a[1] = *(const short8*)(p0 + 512);
      a[2] = *(const short8*)(p0 + 1024);
      a[3] = *(const short8*)(p0 + 1536);
      a[4] = *(const short8*)(p1);
      a[5] = *(const short8*)(p1 + 512);
      a[6] = *(const short8*)(p1 + 1024);
      a[7] = *(const short8*)(p1 + 1536);
      __builtin_amdgcn_s_setprio(1);
      #pragma unroll
      for (int mt = 0; mt < 8; mt++){
        acc[mt][0] = __builtin_amdgcn_mfma_f32_16x16x32_f16(a[mt], bfa, acc[mt][0], 0, 0, 0);
        acc[mt][1] = __builtin_amdgcn_mfma_f32_16x16x32_f16(a[mt], bfb, acc[mt][1], 0, 0, 0);
      }
      __builtin_amdgcn_s_setprio(0);
    }

    // epilogue: bias+relu+mask -> packed fp16 pairs in sval (transpose) ->
    // proj MFMA (K=32, P columns pre-permuted) -> cov store + stats.
    // Single buffer: proj(mt-1) reads are issued BEFORE store(mt) writes;
    // same-wave LDS ops complete in order, compiler preserves aliased order.
    unsigned* sv = &sval[wv][0];
    #pragma unroll
    for (int mt = 0; mt <= 8; mt++){
      if (mt >= 1){
        const int m = mt - 1;
        short8 pa = *(const short8*)&sv[mrow*20 + kb*4];
        f32x4 pc = (f32x4)0.f;
        pc = __builtin_amdgcn_mfma_f32_16x16x32_f16(pa, pbf, pc, 0, 0, 0);
        if (mrow < 8){
          const unsigned long long mwm = (m < 4) ? mw0 : mw1;
          size_t covbase = (((size_t)bt*NH + mrow) * L_) + half*1024 + pbase + m*16 + kb*4;
          uint2 st;
          st.x = (unsigned)f2h(pc[0]) | ((unsigned)f2h(pc[1]) << 16);
          st.y = (unsigned)f2h(pc[2]) | ((unsigned)f2h(pc[3]) << 16);
          *(uint2*)&cov[covbase] = st;
          #pragma unroll
          for (int r = 0; r < 4; r++){
            int bi = (m*16 + kb*4 + r) & 63;
            if (!((mwm >> bi) & 1)){ ssum += pc[r]; ssq += pc[r]*pc[r]; }
          }
        }
      }
      if (mt < 8){
        const unsigned long long mw = (mt < 4) ? mw0 : mw1;
        #pragma unroll
        for (int r = 0; r < 4; r++){
          int bi  = (mt*16 + kb*4 + r) & 63;
          int msk = (int)((mw >> bi) & 1);
          float v0 = fmaxf(acc[mt][0][r] + cb0, 0.f);
          float v1 = fmaxf(acc[mt][1][r] + cb1, 0.f);
          if (msk){ v0 = 0.f; v1 = 0.f; }
          unsigned pd = (unsigned)f2h(v0) | ((unsigned)f2h(v1) << 16);
          sv[(kb*4 + r)*20 + mrow] = pd;
        }
      }
    }
  }

  // stats: fold kb groups (lanes mrow, mrow+16, mrow+32, mrow+48)
  ssum += __shfl_xor(ssum, 16);
  ssum += __shfl_xor(ssum, 32);
  ssq  += __shfl_xor(ssq, 16);
  ssq  += __shfl_xor(ssq, 32);
  if (lane < 8){
    atomicAdd(&slots[(bid & 7)*16 + lane],     ssum);
    atomicAdd(&slots[(bid & 7)*16 + 8 + lane], ssq);
  }
}

// ---------------- K_stats: finalize BN -> per-channel affine ---------------
__global__ void k_stats(const float* __restrict__ slots,
                        const float* __restrict__ cntp,
                        const float* __restrict__ gamma,
                        const float* __restrict__ beta,
                        float* __restrict__ ab)
{
  int tid = threadIdx.x;
  if (tid < 8){
    double s = 0.0, q = 0.0;
    for (int i = 0; i < 8; i++){
      s += (double)slots[i*16 + tid];
      q += (double)slots[i*16 + 8 + tid];
    }
    double cnt  = (double)fmaxf(*cntp, 1.0f);
    double mean = s / cnt;
    double var  = q / cnt - mean*mean;
    float inv = (float)(1.0 / sqrt(var + 1e-5));
    float A = gamma[tid] * inv;
    float Bc = beta[tid] - (float)mean * A;
    ab[tid]     = A;
    ab[8 + tid] = Bc;
  }
}

// ---------------- K_out: normalize + (b,t,n)->(b,n,t) permute --------------
__global__ void k_out(const unsigned short* __restrict__ cov,
                      const unsigned char* __restrict__ mB,
                      const float* __restrict__ ab,
                      float* __restrict__ out)
{
  size_t gid = (size_t)blockIdx.x * 256 + threadIdx.x;
  size_t e = gid * 8;                               // out element base
  int px = (int)(e & 2047);
  size_t r = e >> 11;
  int t = (int)(r & 127); r >>= 7;
  int n = (int)(r & 7);
  int b = (int)(r >> 3);
  const unsigned short* cp = cov + ((((size_t)b*T_ + t)*NH + n) << 11) + px;
  u16x8 cv = *(const u16x8*)cp;
  unsigned long long mm = *(const unsigned long long*)(mB + (size_t)b*L_ + px);
  float A = ab[n], Bc = ab[8 + n];
  float res[8];
  #pragma unroll
  for (int j = 0; j < 8; j++){
    float v = h2f(cv[j]);
    res[j] = ((mm >> (8*j)) & 0xFFull) ? v : (A*v + Bc);  // masked: raw (==0)
  }
  f32x4* o = (f32x4*)(out + e);
  o[0] = (f32x4){res[0], res[1], res[2], res[3]};
  o[1] = (f32x4){res[4], res[5], res[6], res[7]};
}

// ---------------------------------------------------------------------------
extern "C" void kernel_launch(void* const* d_in, const int* in_sizes, int n_in,
                              void* d_out, int out_size, void* d_ws, size_t ws_size,
                              hipStream_t stream)
{
  const float* prev  = (const float*)d_in[0];
  const float* curr  = (const float*)d_in[1];
  const void*  mraw  = d_in[2];
  // d_in[3] = h (unused, constant 32)
  const float* convw = (const float*)d_in[4];
  const float* convb = (const float*)d_in[5];
  const float* projw = (const float*)d_in[6];
  const float* gamma = (const float*)d_in[7];
  const float* beta  = (const float*)d_in[8];
  float* out = (float*)d_out;

  char* ws = (char*)d_ws;
  // layout (bytes): cumIn 67108864 | cov 33554432 | mB 16384 | Wt 26880 |
  //                 Pt 1024 | slots 512 | cnt 64 | ab 64
  unsigned short* cumIn = (unsigned short*)(ws);
  unsigned short* cov   = (unsigned short*)(ws + 67108864);
  unsigned char*  mB    = (unsigned char*) (ws + 100663296);
  unsigned short* Wt    = (unsigned short*)(ws + 100679680);
  unsigned short* Pt    = (unsigned short*)(ws + 100706560);
  float* slots          = (float*)(ws + 100707584);
  float* cntp           = (float*)(ws + 100708096);
  float* ab             = (float*)(ws + 100708160);
  if (ws_size < (size_t)100708224) return;   // clean failure if ws too small

  hipMemsetAsync(slots, 0, 640, stream);     // slots + cntp
  k_front <<<305,  256, 0, stream>>>(prev, curr, (uint2*)cumIn,
                                     convw, projw, mraw, Wt, Pt, mB, cntp);
  k_conv  <<<2048, 256, 0, stream>>>(cumIn, Wt, Pt, mB, convb, cov, slots);
  k_stats <<<1,    64,  0, stream>>>(slots, cntp, gamma, beta, ab);
  k_out   <<<8192, 256, 0, stream>>>(cov, mB, ab, out);
}